// Round 1
// baseline (164.190 us; speedup 1.0000x reference)
//
#include <hip/hip_runtime.h>

// Contrast MHSA: x,y:(4,1024,1024) f32; Wq/Wk/Wv:(1024,1024) f32
// out = (c_att, att) each (4,1024,1024) f32, concatenated (8388608 floats).
//
// Pipeline:
//  1) cvt_bf16: f32 -> bf16 for x, y, Wq, Wk, Wv (into ws)
//  2) gemm_proj (z=0,1,2): Q = 0.125*(x Wq^T) [4096,1024] bf16
//                          K = x Wk^T        [4096,1024] bf16
//                          Vt = (y Wv^T) transposed per-head to [b][h][dv][n] bf16
//  3) attn_fused: per (b,h,128-row tile): two-pass double-softmax attention.

typedef __attribute__((ext_vector_type(8))) short bf16x8;
typedef __attribute__((ext_vector_type(4))) float f32x4;
typedef __attribute__((ext_vector_type(4))) float float4v;
typedef __attribute__((ext_vector_type(2))) unsigned int uint2v;
typedef __attribute__((ext_vector_type(4))) unsigned short ushort4v;

#define DEVINL static __device__ __forceinline__

DEVINL unsigned f2bf_u(float f) {
  unsigned u = __float_as_uint(f);
  return (u + 0x7fffu + ((u >> 16) & 1u)) >> 16;   // RNE
}
DEVINL unsigned short f2bf(float f) { return (unsigned short)f2bf_u(f); }
DEVINL unsigned pack2(float lo, float hi) { return f2bf_u(lo) | (f2bf_u(hi) << 16); }

DEVINL void gload_lds16(const void* g, void* l) {
  __builtin_amdgcn_global_load_lds((const __attribute__((address_space(1))) unsigned int*)g,
                                   (__attribute__((address_space(3))) unsigned int*)l, 16, 0, 0);
}

DEVINL f32x4 mfma16(bf16x8 a, bf16x8 b, f32x4 c) {
  return __builtin_amdgcn_mfma_f32_16x16x32_bf16(a, b, c, 0, 0, 0);
}

// ------------------------- 1) f32 -> bf16 convert -------------------------
__global__ void cvt_bf16(const float* __restrict__ s, unsigned short* __restrict__ d, int n) {
  long long i = (long long)(blockIdx.x * blockDim.x + threadIdx.x) * 8;
  long long stride = (long long)gridDim.x * blockDim.x * 8;
  for (long long e = i; e < n; e += stride) {
    float4v a = *(const float4v*)(s + e);
    float4v b = *(const float4v*)(s + e + 4);
    ushort4v lo = { f2bf(a[0]), f2bf(a[1]), f2bf(a[2]), f2bf(a[3]) };
    ushort4v hi = { f2bf(b[0]), f2bf(b[1]), f2bf(b[2]), f2bf(b[3]) };
    *(ushort4v*)(d + e) = lo;
    *(ushort4v*)(d + e + 4) = hi;
  }
}

// ------------------------- 2) projection GEMM -------------------------
// C[4096,1024] = A[4096,1024] * W^T, W stored [out,in] (i.e. B^T layout).
// 128x128 tile, BK=32, 256 threads (4 waves, 2x2 of 64x64), m97 structure.
__global__ __launch_bounds__(256, 3)
void gemm_proj(const unsigned short* __restrict__ xb, const unsigned short* __restrict__ yb,
               const unsigned short* __restrict__ wq, const unsigned short* __restrict__ wk,
               const unsigned short* __restrict__ wv,
               unsigned short* __restrict__ Qb, unsigned short* __restrict__ Kb,
               unsigned short* __restrict__ Vt) {
  const int z = blockIdx.z;
  const unsigned short* A  = (z == 2) ? yb : xb;
  const unsigned short* Bw = (z == 0) ? wq : ((z == 1) ? wk : wv);

  __shared__ unsigned short lA[128 * 32];
  __shared__ unsigned short lB[128 * 32];

  const int tid = threadIdx.x;
  const int w = tid >> 6, l = tid & 63;
  const int lq = l & 15, lg = l >> 4;
  const int tm = blockIdx.y, tn = blockIdx.x;

  const int srow = l >> 2;            // 0..15 within wave's 16-row stripe
  const int scol = (l & 3) * 8;       // 4 x 8 elems = 16B chunks
  const size_t arow0 = (size_t)tm * 128 + w * 16 + srow;
  const size_t brow0 = (size_t)tn * 128 + w * 16 + srow;
  const int wr = (w >> 1) * 64, wc = (w & 1) * 64;

  f32x4 zero4 = {0.f, 0.f, 0.f, 0.f};
  f32x4 acc[4][4];
#pragma unroll
  for (int m = 0; m < 4; ++m)
#pragma unroll
    for (int n = 0; n < 4; ++n) acc[m][n] = zero4;

  for (int k0 = 0; k0 < 1024; k0 += 32) {
    gload_lds16(A + arow0 * 1024 + k0 + scol,        &lA[w * 512]);
    gload_lds16(A + (arow0 + 64) * 1024 + k0 + scol, &lA[w * 512 + 2048]);
    gload_lds16(Bw + brow0 * 1024 + k0 + scol,        &lB[w * 512]);
    gload_lds16(Bw + (brow0 + 64) * 1024 + k0 + scol, &lB[w * 512 + 2048]);
    __syncthreads();
    bf16x8 af[4], bfr[4];
#pragma unroll
    for (int m = 0; m < 4; ++m) af[m]  = *(const bf16x8*)&lA[(wr + m * 16 + lq) * 32 + lg * 8];
#pragma unroll
    for (int n = 0; n < 4; ++n) bfr[n] = *(const bf16x8*)&lB[(wc + n * 16 + lq) * 32 + lg * 8];
#pragma unroll
    for (int m = 0; m < 4; ++m)
#pragma unroll
      for (int n = 0; n < 4; ++n)
        acc[m][n] = mfma16(af[m], bfr[n], acc[m][n]);
    __syncthreads();
  }

  if (z < 2) {
    unsigned short* O = (z == 0) ? Qb : Kb;
    const float scale = (z == 0) ? 0.125f : 1.0f;   // fold 1/sqrt(dk) into Q
#pragma unroll
    for (int m = 0; m < 4; ++m)
#pragma unroll
      for (int n = 0; n < 4; ++n) {
        int row0 = tm * 128 + wr + m * 16 + lg * 4;
        int col  = tn * 128 + wc + n * 16 + lq;
#pragma unroll
        for (int j = 0; j < 4; ++j)
          O[(size_t)(row0 + j) * 1024 + col] = f2bf(acc[m][n][j] * scale);
      }
  } else {
    // V^T layout: Vt[(b*1024 + col)*1024 + n], col = h*64+dv
#pragma unroll
    for (int m = 0; m < 4; ++m)
#pragma unroll
      for (int n = 0; n < 4; ++n) {
        int row0 = tm * 128 + wr + m * 16 + lg * 4;  // = b*1024 + n0
        int col  = tn * 128 + wc + n * 16 + lq;
        int bb = row0 >> 10, n0 = row0 & 1023;
        uint2v p = { pack2(acc[m][n][0], acc[m][n][1]), pack2(acc[m][n][2], acc[m][n][3]) };
        *(uint2v*)(Vt + ((size_t)(bb * 1024 + col)) * 1024 + n0) = p;
      }
  }
}

// ------------------------- 3) fused double-softmax attention -------------------------
// Block: 256 thr = 4 waves; wave owns 32 q-rows of one (b,h). Grid (8 tiles,16 h,4 b).
// Swapped QK^T: S^T = mfma(K_frag, Q_frag) -> lane holds q = lane&15, m = 16*mg + 4*(lane>>4)+j.
__global__ __launch_bounds__(256, 2)
void attn_fused(const unsigned short* __restrict__ Qb, const unsigned short* __restrict__ Kb,
                const unsigned short* __restrict__ Vt, float* __restrict__ out) {
  const int tid = threadIdx.x;
  const int w = tid >> 6, l = tid & 63;
  const int lq = l & 15, lg = l >> 4;
  const int tile = blockIdx.x, h = blockIdx.y, b = blockIdx.z;
  const int qBase = tile * 128 + w * 32;

  __shared__ unsigned short Plds[4 * 2 * 32 * 72];   // [wave][branch][32 q][72]
  unsigned short* P2 = &Plds[(w * 2 + 0) * 32 * 72];
  unsigned short* Pa = &Plds[(w * 2 + 1) * 32 * 72];

  // Q fragments (already scaled by 0.125): B-operand layout, q = lane&15
  bf16x8 qf[2][2];
#pragma unroll
  for (int qg = 0; qg < 2; ++qg)
#pragma unroll
    for (int kst = 0; kst < 2; ++kst)
      qf[qg][kst] = *(const bf16x8*)(Qb + ((size_t)(b * 1024 + qBase + qg * 16 + lq)) * 1024
                                       + h * 64 + kst * 32 + lg * 8);

  const unsigned short* Kh = Kb + ((size_t)b * 1024) * 1024 + h * 64 + lg * 8;

  // ---- pass 1: per-q-row max and sum of exp over all 1024 m ----
  float rM[2] = { -3.0e38f, -3.0e38f }, rZ[2] = { 0.f, 0.f };
  for (int mg = 0; mg < 64; ++mg) {
    const unsigned short* Km = Kh + ((size_t)(mg * 16 + lq)) * 1024;
    bf16x8 ka0 = *(const bf16x8*)(Km);
    bf16x8 ka1 = *(const bf16x8*)(Km + 32);
#pragma unroll
    for (int qg = 0; qg < 2; ++qg) {
      f32x4 s = {0.f, 0.f, 0.f, 0.f};
      s = mfma16(ka0, qf[qg][0], s);
      s = mfma16(ka1, qf[qg][1], s);
      float fm = fmaxf(fmaxf(s[0], s[1]), fmaxf(s[2], s[3]));
      float nm = fmaxf(rM[qg], fm);
      rZ[qg] = rZ[qg] * __expf(rM[qg] - nm)
             + __expf(s[0] - nm) + __expf(s[1] - nm) + __expf(s[2] - nm) + __expf(s[3] - nm);
      rM[qg] = nm;
    }
  }
#pragma unroll
  for (int qg = 0; qg < 2; ++qg) {
#pragma unroll
    for (int d = 16; d <= 32; d <<= 1) {
      float oM = __shfl_xor(rM[qg], d, 64);
      float oZ = __shfl_xor(rZ[qg], d, 64);
      float nm = fmaxf(rM[qg], oM);
      rZ[qg] = rZ[qg] * __expf(rM[qg] - nm) + oZ * __expf(oM - nm);
      rM[qg] = nm;
    }
  }
  float invZ[2] = { 1.0f / rZ[0], 1.0f / rZ[1] };

  // ---- pass 2: recompute scores; accumulate both branches ----
  float Z2[2] = {0.f, 0.f}, Za[2] = {0.f, 0.f};
  f32x4 zero4 = {0.f, 0.f, 0.f, 0.f};
  f32x4 o2[2][4], oa[2][4];
#pragma unroll
  for (int qg = 0; qg < 2; ++qg)
#pragma unroll
    for (int dvg = 0; dvg < 4; ++dvg) { o2[qg][dvg] = zero4; oa[qg][dvg] = zero4; }

  const unsigned short* Vh = Vt + ((size_t)(b * 1024 + h * 64 + lq)) * 1024 + lg * 8;

  for (int mc = 0; mc < 16; ++mc) {
#pragma unroll
    for (int sub = 0; sub < 4; ++sub) {
      int mg = mc * 4 + sub;
      const unsigned short* Km = Kh + ((size_t)(mg * 16 + lq)) * 1024;
      bf16x8 ka0 = *(const bf16x8*)(Km);
      bf16x8 ka1 = *(const bf16x8*)(Km + 32);
#pragma unroll
      for (int qg = 0; qg < 2; ++qg) {
        f32x4 s = zero4;
        s = mfma16(ka0, qf[qg][0], s);
        s = mfma16(ka1, qf[qg][1], s);
        unsigned pk2[2], pka[2];
#pragma unroll
        for (int jj = 0; jj < 2; ++jj) {
          float d0 = __expf(s[2 * jj]     - rM[qg]) * invZ[qg];   // dist in [0,1]
          float d1 = __expf(s[2 * jj + 1] - rM[qg]) * invZ[qg];
          float w20 = __expf(d0), w21 = __expf(d1);               // softmax(dist) weights
          float wa0 = __builtin_amdgcn_rcpf(w20);                 // exp(-dist)
          float wa1 = __builtin_amdgcn_rcpf(w21);
          Z2[qg] += w20 + w21;
          Za[qg] += wa0 + wa1;
          pk2[jj] = pack2(w20, w21);
          pka[jj] = pack2(wa0, wa1);
        }
        int off = (qg * 16 + lq) * 72 + sub * 16 + lg * 4;
        *(uint2v*)&P2[off] = (uint2v){ pk2[0], pk2[1] };
        *(uint2v*)&Pa[off] = (uint2v){ pka[0], pka[1] };
      }
    }
    // PV for this 64-m chunk, both branches share V fragments
#pragma unroll
    for (int kst2 = 0; kst2 < 2; ++kst2) {
      bf16x8 vf[4];
      const unsigned short* Vm = Vh + mc * 64 + kst2 * 32;
#pragma unroll
      for (int dvg = 0; dvg < 4; ++dvg)
        vf[dvg] = *(const bf16x8*)(Vm + (size_t)dvg * 16 * 1024);
#pragma unroll
      for (int qg = 0; qg < 2; ++qg) {
        bf16x8 a2  = *(const bf16x8*)&P2[(qg * 16 + lq) * 72 + kst2 * 32 + lg * 8];
        bf16x8 aav = *(const bf16x8*)&Pa[(qg * 16 + lq) * 72 + kst2 * 32 + lg * 8];
#pragma unroll
        for (int dvg = 0; dvg < 4; ++dvg) {
          o2[qg][dvg] = mfma16(a2,  vf[dvg], o2[qg][dvg]);
          oa[qg][dvg] = mfma16(aav, vf[dvg], oa[qg][dvg]);
        }
      }
    }
  }

  // normalizers: sum across the 4 lane-groups
#pragma unroll
  for (int qg = 0; qg < 2; ++qg) {
    Z2[qg] += __shfl_xor(Z2[qg], 16, 64); Z2[qg] += __shfl_xor(Z2[qg], 32, 64);
    Za[qg] += __shfl_xor(Za[qg], 16, 64); Za[qg] += __shfl_xor(Za[qg], 32, 64);
  }
  float i2[2] = { 1.0f / Z2[0], 1.0f / Z2[1] };
  float ia[2] = { 1.0f / Za[0], 1.0f / Za[1] };

  // output: D layout row = lg*4+j (q), col = lq (dv); fetch the right 1/Z via shfl
#pragma unroll
  for (int qg = 0; qg < 2; ++qg)
#pragma unroll
    for (int j = 0; j < 4; ++j) {
      int src = lg * 4 + j;                 // lane holding stats for this q-row
      float z2j = __shfl(i2[qg], src, 64);
      float zaj = __shfl(ia[qg], src, 64);
      int nrow = qBase + qg * 16 + lg * 4 + j;
      size_t rb = ((size_t)(b * 1024 + nrow)) * 1024 + h * 64;
#pragma unroll
      for (int dvg = 0; dvg < 4; ++dvg) {
        int dv = dvg * 16 + lq;
        out[rb + dv] = oa[qg][dvg][j] * zaj;                 // c_att (contrast branch)
        out[4194304 + rb + dv] = o2[qg][dvg][j] * z2j;       // att
      }
    }
}

// ------------------------- launch -------------------------
extern "C" void kernel_launch(void* const* d_in, const int* in_sizes, int n_in,
                              void* d_out, int out_size, void* d_ws, size_t ws_size,
                              hipStream_t stream) {
  const float* x  = (const float*)d_in[0];
  const float* y  = (const float*)d_in[1];
  const float* Wq = (const float*)d_in[2];
  const float* Wk = (const float*)d_in[3];
  const float* Wv = (const float*)d_in[4];
  float* out = (float*)d_out;
  char* ws = (char*)d_ws;
  const size_t MB = 1024 * 1024;
  unsigned short* xb  = (unsigned short*)(ws + 0 * MB);
  unsigned short* yb  = (unsigned short*)(ws + 8 * MB);
  unsigned short* wqb = (unsigned short*)(ws + 16 * MB);
  unsigned short* wkb = (unsigned short*)(ws + 18 * MB);
  unsigned short* wvb = (unsigned short*)(ws + 20 * MB);
  unsigned short* Qb  = (unsigned short*)(ws + 22 * MB);
  unsigned short* Kb  = (unsigned short*)(ws + 30 * MB);
  unsigned short* Vt  = (unsigned short*)(ws + 38 * MB);

  cvt_bf16<<<dim3(2048), dim3(256), 0, stream>>>(x, xb, 4 * 1024 * 1024);
  cvt_bf16<<<dim3(2048), dim3(256), 0, stream>>>(y, yb, 4 * 1024 * 1024);
  cvt_bf16<<<dim3(512),  dim3(256), 0, stream>>>(Wq, wqb, 1024 * 1024);
  cvt_bf16<<<dim3(512),  dim3(256), 0, stream>>>(Wk, wkb, 1024 * 1024);
  cvt_bf16<<<dim3(512),  dim3(256), 0, stream>>>(Wv, wvb, 1024 * 1024);

  gemm_proj<<<dim3(8, 32, 3), dim3(256), 0, stream>>>(xb, yb, wqb, wkb, wvb, Qb, Kb, Vt);

  attn_fused<<<dim3(8, 16, 4), dim3(256), 0, stream>>>(Qb, Kb, Vt, out);
}